// Round 4
// baseline (3444.022 us; speedup 1.0000x reference)
//
#include <hip/hip_runtime.h>
#include <math.h>

// Problem constants
#define BATCH 1024
#define CDIM 256
#define NHEADS 8
#define HDIM 32      // head dim
#define NTOK 64      // tokens per window (8x8)
#define SCALE 0.17677669529663687f  // 32^-0.5
#define PLANE 16777216LL            // 1024*256*64 = elements per (real|imag) plane

// ---------------------------------------------------------------------------
// Kernel A: per (local-batch, head) block.  f32 in, f32 mid.
//  Phase 1: qkv = W_qkv(complex, 96 rows for this head) @ x_b (complex 256x64)
//  Phase 2: scatter q,k,v to padded LDS
//  Phase 3: attn = scale * q @ conj(k)^H + bias; magnitude softmax reweight
//  Phase 4: out = attn @ v -> mid[b_local][h*32+d][n] (interleaved complex f32)
// ---------------------------------------------------------------------------
__global__ __launch_bounds__(256) void attn_kernel(
    const float* __restrict__ xr, const float* __restrict__ xi,
    const float* __restrict__ wqr, const float* __restrict__ wqi,
    const float* __restrict__ bias_table, const int* __restrict__ rel_index,
    float* __restrict__ mid, int b0)
{
    const int blk = blockIdx.x;
    const int bl = blk >> 3;        // local batch (indexes mid)
    const int b  = b0 + bl;         // global batch (indexes x)
    const int h = blk & 7;
    const int t = threadIdx.x;

    __shared__ float smem[12672];
    float* q_s    = smem;
    float* k_s    = smem + 4224;
    float* v_s    = smem + 8448;
    float* attn_s = smem;
    float* sx     = smem;          // [16][64][2]
    float* sw     = smem + 2048;   // [96][16][2]

    const int n = t & 63;
    const int g = t >> 6;

    // ---- Phase 1: complex matmul, 96 rows x 64 cols, K=256, 16-wide c tiles
    float accr[24], acci[24];
#pragma unroll
    for (int j = 0; j < 24; j++) { accr[j] = 0.f; acci[j] = 0.f; }

    for (int c0 = 0; c0 < 256; c0 += 16) {
        __syncthreads();
#pragma unroll
        for (int it = 0; it < 4; it++) {
            int idx = t + it * 256;            // < 1024
            int cc = idx >> 6, nn = idx & 63;
            int gidx = ((b * 256 + c0 + cc) * 64) + nn;
            sx[idx * 2 + 0] = xr[gidx];
            sx[idx * 2 + 1] = xi[gidx];
        }
#pragma unroll
        for (int it = 0; it < 6; it++) {
            int idx = t + it * 256;            // < 1536
            int rr = idx >> 4, cc = idx & 15;
            int grow = (rr < 32) ? (h * 32 + rr)
                     : (rr < 64) ? (256 + h * 32 + (rr - 32))
                                 : (512 + h * 32 + (rr - 64));
            int gw = grow * 256 + c0 + cc;
            sw[idx * 2 + 0] = wqr[gw];
            sw[idx * 2 + 1] = wqi[gw];
        }
        __syncthreads();
        for (int cc = 0; cc < 16; cc++) {
            float x_r = sx[(cc * 64 + n) * 2 + 0];
            float x_i = sx[(cc * 64 + n) * 2 + 1];
#pragma unroll
            for (int j = 0; j < 24; j++) {
                int rr = g + 4 * j;
                float w_r = sw[(rr * 16 + cc) * 2 + 0];
                float w_i = sw[(rr * 16 + cc) * 2 + 1];
                accr[j] += w_r * x_r - w_i * x_i;
                acci[j] += w_r * x_i + w_i * x_r;
            }
        }
    }
    __syncthreads();

    // ---- Phase 2: scatter q,k,v (padded rows of 33 to break bank conflicts)
#pragma unroll
    for (int j = 0; j < 24; j++) {
        int rr = g + 4 * j;
        float* dst = (rr < 32) ? q_s : (rr < 64) ? k_s : v_s;
        int d = rr & 31;
        dst[(n * 33 + d) * 2 + 0] = accr[j];
        dst[(n * 33 + d) * 2 + 1] = acci[j];
    }
    __syncthreads();

    // ---- Phase 3: attention scores + magnitude softmax
    {
        const int an = t >> 2;   // query row, 0..63
        const int mg = t & 3;    // key-group
        float ar[16], ai[16];
#pragma unroll
        for (int jj = 0; jj < 16; jj++) { ar[jj] = 0.f; ai[jj] = 0.f; }

        for (int d = 0; d < 32; d++) {
            float q_r = q_s[(an * 33 + d) * 2 + 0];
            float q_i = q_s[(an * 33 + d) * 2 + 1];
#pragma unroll
            for (int jj = 0; jj < 16; jj++) {
                int m = mg + 4 * jj;
                float k_r = k_s[(m * 33 + d) * 2 + 0];
                float k_i = k_s[(m * 33 + d) * 2 + 1];
                ar[jj] += q_r * k_r + q_i * k_i;   // q * conj(k): real
                ai[jj] += q_i * k_r - q_r * k_i;   // imag
            }
        }
        float mag[16];
        float mx = -1e30f;
#pragma unroll
        for (int jj = 0; jj < 16; jj++) {
            int m = mg + 4 * jj;
            ar[jj] = ar[jj] * SCALE + bias_table[rel_index[an * 64 + m] * 8 + h];
            ai[jj] *= SCALE;
            mag[jj] = sqrtf(ar[jj] * ar[jj] + ai[jj] * ai[jj]);
            mx = fmaxf(mx, mag[jj]);
        }
        mx = fmaxf(mx, __shfl_xor(mx, 1));
        mx = fmaxf(mx, __shfl_xor(mx, 2));
        float se = 0.f;
#pragma unroll
        for (int jj = 0; jj < 16; jj++) se += expf(mag[jj] - mx);
        se += __shfl_xor(se, 1);
        se += __shfl_xor(se, 2);
        float inv = 1.0f / se;
#pragma unroll
        for (int jj = 0; jj < 16; jj++) {
            float wgt = expf(mag[jj] - mx) * inv;
            float f = wgt / (mag[jj] + 1e-8f);
            ar[jj] *= f;
            ai[jj] *= f;
        }
        __syncthreads();   // q/k reads done; attn_s aliases them
#pragma unroll
        for (int jj = 0; jj < 16; jj++) {
            int m = mg + 4 * jj;
            attn_s[(an * 65 + m) * 2 + 0] = ar[jj];
            attn_s[(an * 65 + m) * 2 + 1] = ai[jj];
        }
    }
    __syncthreads();

    // ---- Phase 4: out[n][d] = sum_m attn[n][m] * v[m][d]
    {
        const int d = t & 31;
        const int ng = t >> 5;   // 0..7
        float outr[8], outi[8];
#pragma unroll
        for (int jj = 0; jj < 8; jj++) { outr[jj] = 0.f; outi[jj] = 0.f; }

        for (int m = 0; m < 64; m++) {
            float v_r = v_s[(m * 33 + d) * 2 + 0];
            float v_i = v_s[(m * 33 + d) * 2 + 1];
#pragma unroll
            for (int jj = 0; jj < 8; jj++) {
                int nn = ng + 8 * jj;
                float a_r = attn_s[(nn * 65 + m) * 2 + 0];
                float a_i = attn_s[(nn * 65 + m) * 2 + 1];
                outr[jj] += a_r * v_r - a_i * v_i;
                outi[jj] += a_r * v_i + a_i * v_r;
            }
        }
        float2* midp = (float2*)mid;
#pragma unroll
        for (int jj = 0; jj < 8; jj++) {
            int nn = ng + 8 * jj;
            midp[(bl * 256 + h * 32 + d) * 64 + nn] = make_float2(outr[jj], outi[jj]);
        }
    }
}

// ---------------------------------------------------------------------------
// Kernel B: final complex projection  y[b][o][n] = sum_c w_proj[o][c]*mid[bl][c][n]
// Output: PLANAR f32 — real plane [1024][256][64] then imag plane.
// ---------------------------------------------------------------------------
__global__ __launch_bounds__(256) void proj_kernel(
    const float* __restrict__ mid,
    const float* __restrict__ wpr, const float* __restrict__ wpi,
    float* __restrict__ out, int b0, long long out_floats)
{
    const int blk = blockIdx.x;
    const int bl = blk >> 2;
    const int b  = b0 + bl;
    const int qtr = blk & 3;
    const int t = threadIdx.x;
    const int n = t & 63;
    const int g = t >> 6;

    __shared__ float sx[2048];   // [16][64][2]
    __shared__ float sw[2048];   // [64][16][2]

    float accr[16], acci[16];
#pragma unroll
    for (int j = 0; j < 16; j++) { accr[j] = 0.f; acci[j] = 0.f; }

    const float2* midp = (const float2*)mid;
    for (int c0 = 0; c0 < 256; c0 += 16) {
        __syncthreads();
#pragma unroll
        for (int it = 0; it < 4; it++) {
            int idx = t + it * 256;
            int cc = idx >> 6, nn = idx & 63;
            float2 v = midp[(bl * 256 + c0 + cc) * 64 + nn];
            sx[idx * 2 + 0] = v.x;
            sx[idx * 2 + 1] = v.y;
        }
#pragma unroll
        for (int it = 0; it < 4; it++) {
            int idx = t + it * 256;
            int rr = idx >> 4, cc = idx & 15;
            int o = qtr * 64 + rr;
            sw[idx * 2 + 0] = wpr[o * 256 + c0 + cc];
            sw[idx * 2 + 1] = wpi[o * 256 + c0 + cc];
        }
        __syncthreads();
        for (int cc = 0; cc < 16; cc++) {
            float x_r = sx[(cc * 64 + n) * 2 + 0];
            float x_i = sx[(cc * 64 + n) * 2 + 1];
#pragma unroll
            for (int j = 0; j < 16; j++) {
                int rr = g + 4 * j;
                float w_r = sw[(rr * 16 + cc) * 2 + 0];
                float w_i = sw[(rr * 16 + cc) * 2 + 1];
                accr[j] += w_r * x_r - w_i * x_i;
                acci[j] += w_r * x_i + w_i * x_r;
            }
        }
    }

    // Planar store: real plane then imag plane. Guards make a single-plane
    // (real-only) output buffer safe too: imag writes get dropped, no fault.
#pragma unroll
    for (int j = 0; j < 16; j++) {
        int o = qtr * 64 + g + 4 * j;
        long long idx = ((long long)(b * 256 + o)) * 64 + n;
        if (idx < out_floats)
            out[idx] = accr[j];
        if (PLANE + idx < out_floats)
            out[PLANE + idx] = acci[j];
    }
}

extern "C" void kernel_launch(void* const* d_in, const int* in_sizes, int n_in,
                              void* d_out, int out_size, void* d_ws, size_t ws_size,
                              hipStream_t stream) {
    const float* xr  = (const float*)d_in[0];
    const float* xi  = (const float*)d_in[1];
    const float* wqr = (const float*)d_in[2];
    const float* wqi = (const float*)d_in[3];
    const float* wpr = (const float*)d_in[4];
    const float* wpi = (const float*)d_in[5];
    const float* bt  = (const float*)d_in[6];
    const int*   ri  = (const int*)d_in[7];

    float* mid = (float*)d_ws;

    // Chunk the batch dim so mid (f32 interleaved complex) fits in ws_size.
    const size_t bytes_per_batch = (size_t)CDIM * NTOK * 2 * sizeof(float); // 128 KiB
    size_t chunk_sz = ws_size / bytes_per_batch;
    if (chunk_sz > BATCH) chunk_sz = BATCH;
    if (chunk_sz < 1) return;   // cannot run — avoids a fault
    int chunk = (int)chunk_sz;

    for (int b0 = 0; b0 < BATCH; b0 += chunk) {
        int nb = BATCH - b0;
        if (nb > chunk) nb = chunk;
        attn_kernel<<<nb * NHEADS, 256, 0, stream>>>(xr, xi, wqr, wqi, bt, ri, mid, b0);
        proj_kernel<<<nb * 4, 256, 0, stream>>>(mid, wpr, wpi, (float*)d_out,
                                                b0, (long long)out_size);
    }
}

// Round 6
// 1794.054 us; speedup vs baseline: 1.9197x; 1.9197x over previous
//
#include <hip/hip_runtime.h>
#include <math.h>

#define BATCH 1024
#define CDIM 256
#define NHEADS 8
#define NTOK 64
#define SCALE 0.17677669529663687f  // 32^-0.5

typedef _Float16 h8 __attribute__((ext_vector_type(8)));
typedef _Float16 h2 __attribute__((ext_vector_type(2)));
typedef float f4 __attribute__((ext_vector_type(4)));

#define MFMA16(a, b, c) __builtin_amdgcn_mfma_f32_16x16x32_f16((a), (b), (c), 0, 0, 0)

// ---- LDS plane offsets (in _Float16 units) ----
// Phase 1 staging:
#define WAH_O 0        // [96][72] hi of (wr, -wi)
#define WAL_O 6912     // [96][72] lo
#define XCH_O 13824    // [64][72] hi of (xr, xi)
#define XCL_O 18432    // [64][72] lo
// Phase 2+ (aliases staging, phase-ordered):
#define QAH_O 0        // [64][72] hi of (qr, qi)
#define QAL_O 4608     // [64][72] lo
#define KAH_O 9216     // [64][72] hi of (kr, ki)
#define KAL_O 13824    // [64][72] lo
#define VA_O  18432    // [32][136] (vr, -vi)  rows = d, cols = 2*tok  (f16 single)
#define PC_O  22784    // [64][136] (pr, pi)   rows = query, cols = 2*key (f16 single)
#define LDS_HALFS 31488   // 62976 bytes

// split v into f16 hi + f16 lo (residual ~2^-22 relative)
__device__ __forceinline__ void fsplit(float v, _Float16& hi, _Float16& lo) {
    _Float16 h = (_Float16)v;
    hi = h;
    lo = (_Float16)(v - (float)h);
}

// word (a,b) -> (-b? ...): rotate halves then negate LOW half: (a,b)->(b? ...)
// For W/V composite: (p, -q) -> (q, p).  For Q: use rot_neg_hi: (p,q) -> (q,-p).
__device__ __forceinline__ h8 rot_neg_lo(h8 a) {
    union { h8 h; unsigned int w[4]; } u; u.h = a;
#pragma unroll
    for (int i = 0; i < 4; i++) {
        unsigned int t = u.w[i];
        t = (t >> 16) | (t << 16);
        u.w[i] = t ^ 0x00008000u;
    }
    return u.h;
}
__device__ __forceinline__ h8 rot_neg_hi(h8 a) {
    union { h8 h; unsigned int w[4]; } u; u.h = a;
#pragma unroll
    for (int i = 0; i < 4; i++) {
        unsigned int t = u.w[i];
        t = (t >> 16) | (t << 16);
        u.w[i] = t ^ 0x80000000u;
    }
    return u.h;
}

// ---------------------------------------------------------------------------
// MFMA attention kernel: one block per (local-batch, head), 256 thr = 4 waves.
// Split-f16 precision on QKV-proj inputs and Q/K; plain f16 on P/V.
// ---------------------------------------------------------------------------
__global__ __launch_bounds__(256) void attn_kernel(
    const float* __restrict__ xr, const float* __restrict__ xi,
    const float* __restrict__ wqr, const float* __restrict__ wqi,
    const float* __restrict__ bias_table, const int* __restrict__ rel_index,
    float* __restrict__ mid, int b0)
{
    const int blk = blockIdx.x;
    const int bl = blk >> 3;
    const int b  = b0 + bl;
    const int h  = blk & 7;
    const int t  = threadIdx.x;
    const int ln   = t & 15;         // frag 16-index
    const int quad = (t >> 4) & 3;   // frag k-quad
    const int wv   = t >> 6;         // wave id = token-group

    __shared__ alignas(16) _Float16 lds[LDS_HALFS];

    // ---- Phase 1: QKV projection. acc tiles: mt 0,1=q 2,3=k 4,5=v
    f4 accR[6], accI[6];
#pragma unroll
    for (int m = 0; m < 6; m++) {
        accR[m] = (f4){0.f, 0.f, 0.f, 0.f};
        accI[m] = (f4){0.f, 0.f, 0.f, 0.f};
    }

    for (int chunk = 0; chunk < 8; chunk++) {   // 32 channels per chunk
        __syncthreads();
        // stage W: 96 rows x 32 ch, float4 loads, h8 hi/lo writes
#pragma unroll
        for (int i = 0; i < 3; i++) {
            int p = t + i * 256;               // < 768
            int row = p >> 3, c4 = p & 7;
            int grow = (row < 32) ? (h * 32 + row)
                     : (row < 64) ? (256 + h * 32 + (row - 32))
                                  : (512 + h * 32 + (row - 64));
            int c = chunk * 32 + c4 * 4;
            float4 wr4 = *(const float4*)&wqr[grow * 256 + c];
            float4 wi4 = *(const float4*)&wqi[grow * 256 + c];
            const float* wrp = &wr4.x;
            const float* wip = &wi4.x;
            h8 hi, lo;
#pragma unroll
            for (int j = 0; j < 4; j++) {
                _Float16 h0, l0, h1, l1;
                fsplit(wrp[j], h0, l0);
                fsplit(-wip[j], h1, l1);
                hi[2 * j] = h0; hi[2 * j + 1] = h1;
                lo[2 * j] = l0; lo[2 * j + 1] = l1;
            }
            *(h8*)&lds[WAH_O + row * 72 + 8 * c4] = hi;
            *(h8*)&lds[WAL_O + row * 72 + 8 * c4] = lo;
        }
        // stage X transposed: [tok][(xr,xi) pairs], h8 hi/lo writes
#pragma unroll
        for (int i = 0; i < 2; i++) {
            int p = t + i * 256;               // < 512
            int tok = p & 63, c4g = p >> 6;    // c4g 0..7
            int c = chunk * 32 + c4g * 4;
            h8 hi, lo;
#pragma unroll
            for (int j = 0; j < 4; j++) {
                float xrv = xr[(b * 256 + c + j) * 64 + tok];
                float xiv = xi[(b * 256 + c + j) * 64 + tok];
                _Float16 h0, l0, h1, l1;
                fsplit(xrv, h0, l0);
                fsplit(xiv, h1, l1);
                hi[2 * j] = h0; hi[2 * j + 1] = h1;
                lo[2 * j] = l0; lo[2 * j + 1] = l1;
            }
            *(h8*)&lds[XCH_O + tok * 72 + 8 * c4g] = hi;
            *(h8*)&lds[XCL_O + tok * 72 + 8 * c4g] = lo;
        }
        __syncthreads();
#pragma unroll
        for (int ks = 0; ks < 2; ks++) {
            h8 bxh = *(const h8*)&lds[XCH_O + (wv * 16 + ln) * 72 + ks * 32 + quad * 8];
            h8 bxl = *(const h8*)&lds[XCL_O + (wv * 16 + ln) * 72 + ks * 32 + quad * 8];
#pragma unroll
            for (int mt = 0; mt < 6; mt++) {
                h8 wah = *(const h8*)&lds[WAH_O + (mt * 16 + ln) * 72 + ks * 32 + quad * 8];
                h8 wal = *(const h8*)&lds[WAL_O + (mt * 16 + ln) * 72 + ks * 32 + quad * 8];
                h8 wbh = rot_neg_lo(wah);
                h8 wbl = rot_neg_lo(wal);
                accR[mt] = MFMA16(wah, bxh, accR[mt]);
                accR[mt] = MFMA16(wah, bxl, accR[mt]);
                accR[mt] = MFMA16(wal, bxh, accR[mt]);
                accI[mt] = MFMA16(wbh, bxh, accI[mt]);
                accI[mt] = MFMA16(wbh, bxl, accI[mt]);
                accI[mt] = MFMA16(wbl, bxh, accI[mt]);
            }
        }
    }
    __syncthreads();

    // ---- Phase 2: scatter q,k (split hi/lo) and v (single f16) to LDS
    {
        const int tok = wv * 16 + ln;
        // q -> QAH/QAL = hi/lo of (qr, qi)
#pragma unroll
        for (int mt = 0; mt < 2; mt++) {
            int d0 = mt * 16 + quad * 4;
            h8 hi, lo;
#pragma unroll
            for (int r = 0; r < 4; r++) {
                _Float16 h0, l0, h1, l1;
                fsplit(accR[mt][r], h0, l0);
                fsplit(accI[mt][r], h1, l1);
                hi[2 * r] = h0; hi[2 * r + 1] = h1;
                lo[2 * r] = l0; lo[2 * r + 1] = l1;
            }
            *(h8*)&lds[QAH_O + tok * 72 + 2 * d0] = hi;
            *(h8*)&lds[QAL_O + tok * 72 + 2 * d0] = lo;
        }
        // k -> KAH/KAL = hi/lo of (kr, ki)
#pragma unroll
        for (int mt = 2; mt < 4; mt++) {
            int d0 = (mt - 2) * 16 + quad * 4;
            h8 hi, lo;
#pragma unroll
            for (int r = 0; r < 4; r++) {
                _Float16 h0, l0, h1, l1;
                fsplit(accR[mt][r], h0, l0);
                fsplit(accI[mt][r], h1, l1);
                hi[2 * r] = h0; hi[2 * r + 1] = h1;
                lo[2 * r] = l0; lo[2 * r + 1] = l1;
            }
            *(h8*)&lds[KAH_O + tok * 72 + 2 * d0] = hi;
            *(h8*)&lds[KAL_O + tok * 72 + 2 * d0] = lo;
        }
        // v -> VA[d][2tok] = (vr, -vi), f16 single
#pragma unroll
        for (int mt = 4; mt < 6; mt++) {
#pragma unroll
            for (int r = 0; r < 4; r++) {
                int d = (mt - 4) * 16 + quad * 4 + r;
                h2 va = {(_Float16)accR[mt][r], (_Float16)(-accI[mt][r])};
                *(h2*)&lds[VA_O + d * 136 + 2 * tok] = va;
            }
        }
    }
    __syncthreads();

    // ---- Phase 3: S = scale*(Q conj(K)^H) + bias; magnitude softmax; P -> LDS
    {
        f4 sR[4], sI[4];
#pragma unroll
        for (int m = 0; m < 4; m++) {
            sR[m] = (f4){0.f, 0.f, 0.f, 0.f};
            sI[m] = (f4){0.f, 0.f, 0.f, 0.f};
        }
#pragma unroll
        for (int ks = 0; ks < 2; ks++) {
            h8 qh = *(const h8*)&lds[QAH_O + (wv * 16 + ln) * 72 + ks * 32 + quad * 8];
            h8 ql = *(const h8*)&lds[QAL_O + (wv * 16 + ln) * 72 + ks * 32 + quad * 8];
            h8 qbh = rot_neg_hi(qh);   // (qi, -qr)
            h8 qbl = rot_neg_hi(ql);
#pragma unroll
            for (int mt = 0; mt < 4; mt++) {
                h8 kh = *(const h8*)&lds[KAH_O + (mt * 16 + ln) * 72 + ks * 32 + quad * 8];
                h8 kl = *(const h8*)&lds[KAL_O + (mt * 16 + ln) * 72 + ks * 32 + quad * 8];
                sR[mt] = MFMA16(qh, kh, sR[mt]);
                sR[mt] = MFMA16(qh, kl, sR[mt]);
                sR[mt] = MFMA16(ql, kh, sR[mt]);
                sI[mt] = MFMA16(qbh, kh, sI[mt]);
                sI[mt] = MFMA16(qbh, kl, sI[mt]);
                sI[mt] = MFMA16(qbl, kh, sI[mt]);
            }
        }
#pragma unroll
        for (int r = 0; r < 4; r++) {
            int qrow = wv * 16 + quad * 4 + r;
            float pr[4], pi[4], mg[4], e[4];
            float mx = -1e30f;
#pragma unroll
            for (int mt = 0; mt < 4; mt++) {
                int mcol = mt * 16 + ln;
                float bias = bias_table[rel_index[qrow * 64 + mcol] * 8 + h];
                float srv = sR[mt][r] * SCALE + bias;
                float siv = sI[mt][r] * SCALE;
                pr[mt] = srv; pi[mt] = siv;
                mg[mt] = sqrtf(srv * srv + siv * siv);
                mx = fmaxf(mx, mg[mt]);
            }
            mx = fmaxf(mx, __shfl_xor(mx, 1));
            mx = fmaxf(mx, __shfl_xor(mx, 2));
            mx = fmaxf(mx, __shfl_xor(mx, 4));
            mx = fmaxf(mx, __shfl_xor(mx, 8));
            float se = 0.f;
#pragma unroll
            for (int mt = 0; mt < 4; mt++) { e[mt] = expf(mg[mt] - mx); se += e[mt]; }
            se += __shfl_xor(se, 1);
            se += __shfl_xor(se, 2);
            se += __shfl_xor(se, 4);
            se += __shfl_xor(se, 8);
            float inv = 1.0f / se;
#pragma unroll
            for (int mt = 0; mt < 4; mt++) {
                float f = e[mt] * inv / (mg[mt] + 1e-8f);
                h2 p = {(_Float16)(pr[mt] * f), (_Float16)(pi[mt] * f)};
                *(h2*)&lds[PC_O + qrow * 136 + 2 * (mt * 16 + ln)] = p;
            }
        }
    }
    __syncthreads();

    // ---- Phase 4: O = P V (complex), VB derived in-register
    {
        f4 oR[2], oI[2];
#pragma unroll
        for (int m = 0; m < 2; m++) {
            oR[m] = (f4){0.f, 0.f, 0.f, 0.f};
            oI[m] = (f4){0.f, 0.f, 0.f, 0.f};
        }
#pragma unroll
        for (int ks = 0; ks < 4; ks++) {
            h8 ap = *(const h8*)&lds[PC_O + (wv * 16 + ln) * 136 + ks * 32 + quad * 8];
#pragma unroll
            for (int dt = 0; dt < 2; dt++) {
                h8 va = *(const h8*)&lds[VA_O + (dt * 16 + ln) * 136 + ks * 32 + quad * 8];
                h8 vb = rot_neg_lo(va);    // (vi, vr)
                oR[dt] = MFMA16(ap, va, oR[dt]);
                oI[dt] = MFMA16(ap, vb, oI[dt]);
            }
        }
        float2* midp = (float2*)mid;
#pragma unroll
        for (int dt = 0; dt < 2; dt++) {
            int c = h * 32 + dt * 16 + ln;
            long long base = ((long long)(bl * 256 + c)) * 64 + wv * 16 + quad * 4;
            f4 s0 = {oR[dt][0], oI[dt][0], oR[dt][1], oI[dt][1]};
            f4 s1 = {oR[dt][2], oI[dt][2], oR[dt][3], oI[dt][3]};
            *(f4*)&midp[base] = s0;
            *(f4*)&midp[base + 2] = s1;
        }
    }
}

// ---------------------------------------------------------------------------
// Kernel B (unchanged, known-good): complex projection, planar f32 output.
// ---------------------------------------------------------------------------
#define PLANE 16777216LL
__global__ __launch_bounds__(256) void proj_kernel(
    const float* __restrict__ mid,
    const float* __restrict__ wpr, const float* __restrict__ wpi,
    float* __restrict__ out, int b0, long long out_floats)
{
    const int blk = blockIdx.x;
    const int bl = blk >> 2;
    const int b  = b0 + bl;
    const int qtr = blk & 3;
    const int t = threadIdx.x;
    const int n = t & 63;
    const int g = t >> 6;

    __shared__ float sx[2048];
    __shared__ float sw[2048];

    float accr[16], acci[16];
#pragma unroll
    for (int j = 0; j < 16; j++) { accr[j] = 0.f; acci[j] = 0.f; }

    const float2* midp = (const float2*)mid;
    for (int c0 = 0; c0 < 256; c0 += 16) {
        __syncthreads();
#pragma unroll
        for (int it = 0; it < 4; it++) {
            int idx = t + it * 256;
            int cc = idx >> 6, nn = idx & 63;
            float2 v = midp[(bl * 256 + c0 + cc) * 64 + nn];
            sx[idx * 2 + 0] = v.x;
            sx[idx * 2 + 1] = v.y;
        }
#pragma unroll
        for (int it = 0; it < 4; it++) {
            int idx = t + it * 256;
            int rr = idx >> 4, cc = idx & 15;
            int o = qtr * 64 + rr;
            sw[idx * 2 + 0] = wpr[o * 256 + c0 + cc];
            sw[idx * 2 + 1] = wpi[o * 256 + c0 + cc];
        }
        __syncthreads();
        for (int cc = 0; cc < 16; cc++) {
            float x_r = sx[(cc * 64 + n) * 2 + 0];
            float x_i = sx[(cc * 64 + n) * 2 + 1];
#pragma unroll
            for (int j = 0; j < 16; j++) {
                int rr = g + 4 * j;
                float w_r = sw[(rr * 16 + cc) * 2 + 0];
                float w_i = sw[(rr * 16 + cc) * 2 + 1];
                accr[j] += w_r * x_r - w_i * x_i;
                acci[j] += w_r * x_i + w_i * x_r;
            }
        }
    }

#pragma unroll
    for (int j = 0; j < 16; j++) {
        int o = qtr * 64 + g + 4 * j;
        long long idx = ((long long)(b * 256 + o)) * 64 + n;
        if (idx < out_floats)
            out[idx] = accr[j];
        if (PLANE + idx < out_floats)
            out[PLANE + idx] = acci[j];
    }
}

extern "C" void kernel_launch(void* const* d_in, const int* in_sizes, int n_in,
                              void* d_out, int out_size, void* d_ws, size_t ws_size,
                              hipStream_t stream) {
    const float* xr  = (const float*)d_in[0];
    const float* xi  = (const float*)d_in[1];
    const float* wqr = (const float*)d_in[2];
    const float* wqi = (const float*)d_in[3];
    const float* wpr = (const float*)d_in[4];
    const float* wpi = (const float*)d_in[5];
    const float* bt  = (const float*)d_in[6];
    const int*   ri  = (const int*)d_in[7];

    float* mid = (float*)d_ws;

    const size_t bytes_per_batch = (size_t)CDIM * NTOK * 2 * sizeof(float); // 128 KiB
    size_t chunk_sz = ws_size / bytes_per_batch;
    if (chunk_sz > BATCH) chunk_sz = BATCH;
    if (chunk_sz < 1) return;
    int chunk = (int)chunk_sz;

    for (int b0 = 0; b0 < BATCH; b0 += chunk) {
        int nb = BATCH - b0;
        if (nb > chunk) nb = chunk;
        attn_kernel<<<nb * NHEADS, 256, 0, stream>>>(xr, xi, wqr, wqi, bt, ri, mid, b0);
        proj_kernel<<<nb * 4, 256, 0, stream>>>(mid, wpr, wpi, (float*)d_out,
                                                b0, (long long)out_size);
    }
}